// Round 13
// baseline (227.999 us; speedup 1.0000x reference)
//
#include <hip/hip_runtime.h>
#include <hip/hip_fp16.h>
#include <cstdint>

#define V_N 50000
#define E_N 800000
#define NODE_IN 128
#define EDGE_IN 16
#define HF 128
#define NEG_SLOPE 0.2f
#define NBUCKET 782     // ceil(50000/64) coarse dst buckets (dst>>6)
#define NPART 1563      // edge partitions of 512 (last partial: 256)
#define PSZ 512
#define CAP 2048        // fixed recb capacity per bucket (expected 1024)
#define LCAP 1536       // LDS record capacity in k_fuse (expected 1024, +16sigma)
#define NSCAN 49        // ceil(NBUCKET/16) scan blocks, 16 bins each
#define PPG 98          // parts per group: ceil(NPART/16)
#define NODE_BLKS 1563  // ceil(50000/32)
#define PREP_BLKS 64

// ---- workspace layout (4-byte word offsets) ----
#define OFF_FT    0         // V*64 words (f16 ft, head-major)
#define OFF_EL    3200000   // V*4
#define OFF_ER    3400000   // V*4
#define OFF_H     3600000   // NPART*NBUCKET ints = 1222266 (H[part][bin])
#define OFF_BSUM  4822272   // NBUCKET ints (+pad)
#define OFF_WATT  4823056   // 64
#define OFF_BFRAG 4823120   // 16384 words (16B-aligned)
#define OFF_RECB  4839504   // NBUCKET*CAP*4 words = 6406144 (16B-aligned)
// total ~11.25M words = 45.0 MB

typedef short bf16x8 __attribute__((ext_vector_type(8)));
typedef float f32x4 __attribute__((ext_vector_type(4)));

__device__ __forceinline__ unsigned short f2bf(float f) {
    unsigned u = __float_as_uint(f);
    u += 0x7fffu + ((u >> 16) & 1u);   // round-to-nearest-even
    return (unsigned short)(u >> 16);
}
__device__ __forceinline__ unsigned pk2(float lo, float hi) {
    return (unsigned)f2bf(lo) | ((unsigned)f2bf(hi) << 16);
}
__device__ __forceinline__ float bflo(unsigned w) { return __uint_as_float(w << 16); }
__device__ __forceinline__ float bfhi(unsigned w) { return __uint_as_float(w & 0xffff0000u); }

typedef __fp16 fp16x2 __attribute__((ext_vector_type(2)));
__device__ __forceinline__ unsigned pkh2(float a, float b) {
    fp16x2 h = __builtin_amdgcn_cvt_pkrtz(a, b);   // v_cvt_pkrtz_f16_f32
    return __builtin_bit_cast(unsigned, h);
}
__device__ __forceinline__ __half2 u2h(unsigned u) {
    return __builtin_bit_cast(__half2, u);
}
__device__ __forceinline__ unsigned h2u(__half2 h) {
    return __builtin_bit_cast(unsigned, h);
}

// K1: prep (blocks < PREP_BLKS: watt + bfrag) ∥ bucket-hist (LDS, no global
// atomics): partition hb covers edges [hb*512, hb*512+512).
// H row-major by partition: H[hb*NBUCKET + bin] -> contiguous row write.
__global__ __launch_bounds__(256) void k_prephist(
    const float* __restrict__ We, const float* __restrict__ attn_e,
    const float* __restrict__ Wn, const float* __restrict__ Wr,
    const int* __restrict__ dst,
    float* __restrict__ watt, unsigned* __restrict__ bfrag,
    int* __restrict__ H)
{
    const int t = threadIdx.x;
    if (blockIdx.x >= PREP_BLKS) {
        int hb = blockIdx.x - PREP_BLKS;
        __shared__ int h[NBUCKET];
        for (int i = t; i < NBUCKET; i += 256) h[i] = 0;
        __syncthreads();
        #pragma unroll
        for (int c = 0; c < 2; c++) {
            int e = hb * PSZ + c * 256 + t;
            if (e < E_N) atomicAdd(&h[dst[e] >> 6], 1);
        }
        __syncthreads();
        for (int i = t; i < NBUCKET; i += 256) H[hb * NBUCKET + i] = h[i];
        return;
    }
    int g = blockIdx.x * 256 + t;
    if (blockIdx.x == 0 && t < 64) {
        int k = t >> 2, hh = t & 3;
        float s = 0.f;
        #pragma unroll
        for (int f = 0; f < 32; f++)
            s += We[k * HF + hh * 32 + f] * attn_e[hh * 32 + f];
        watt[k * 4 + hh] = s;
    }
    // g < 16384 always (64 blocks x 256)
    {
        int c    = g >> 8;
        int lane = (g >> 2) & 63;
        int jp   = g & 3;
        int nt = c >> 2, ks = c & 3;
        int col = nt * 16 + (lane & 15);
        int k   = ks * 32 + (lane >> 4) * 8 + jp * 2;
        const float* W = (col < 128) ? Wn : Wr;
        int cc = col & 127;
        float x0 = W[(size_t)k * 128 + cc];
        float x1 = W[(size_t)(k + 1) * 128 + cc];
        bfrag[g] = pk2(x0, x1);
    }
}

// K2: blocks [0,NSCAN) = tiled cursor scan (16 bins/block, 16 part-groups:
// the 16 lanes of a group read 16 CONSECUTIVE bins = one 64B line per
// (part, bin-chunk) -> H read+written exactly once, coalesced; per-bin
// cross-group prefix via 16-step LDS scan; absolute cursors via bin*CAP
// base) ∥ node MFMA. Both halves depend only on K1.
__global__ __launch_bounds__(256) void k_nodescan(
    const float* __restrict__ nf, const unsigned* __restrict__ bfragw,
    const float* __restrict__ attn_l, const float* __restrict__ attn_r,
    const float* __restrict__ bias,
    unsigned* __restrict__ ftw, float* __restrict__ el,
    float* __restrict__ er, float* __restrict__ out,
    int* __restrict__ H, int* __restrict__ binsum)
{
    __shared__ __align__(16) float sSf[32 * 140];
    unsigned short* sA = (unsigned short*)sSf;      // stride 136 bf16/row

    if (blockIdx.x < NSCAN) {
        int* ssum = (int*)sSf;
        const int t = threadIdx.x;
        const int bi = t & 15, bg = t >> 4;
        const int bin = blockIdx.x * 16 + bi;
        const int p0 = bg * PPG;
        const int p1 = min(p0 + PPG, NPART);
        int ls = 0;
        if (bin < NBUCKET)
            for (int p = p0; p < p1; p++) ls += H[p * NBUCKET + bin];
        ssum[t] = ls;
        __syncthreads();
        // per-bin inclusive scan over the 16 groups (stride-16 in LDS)
        #pragma unroll
        for (int off = 1; off < 16; off <<= 1) {
            int u = (bg >= off) ? ssum[t - off * 16] : 0;
            __syncthreads();
            ssum[t] += u;
            __syncthreads();
        }
        if (bin < NBUCKET) {
            int c = bin * CAP + ssum[t] - ls;   // exclusive prefix
            for (int p = p0; p < p1; p++) {
                int v = H[p * NBUCKET + bin];
                H[p * NBUCKET + bin] = c;
                c += v;
            }
            if (bg == 15) binsum[bin] = ssum[t];
        }
        return;
    }

    const int t = threadIdx.x;
    const int lane = t & 63;
    const int w = t >> 6;                            // == head
    const int nb = (blockIdx.x - NSCAN) * 32;
    const int n15 = lane & 15;
    const int q = lane >> 4;
    const unsigned short* bfrag = (const unsigned short*)bfragw;

    #pragma unroll
    for (int i = 0; i < 4; i++) {
        int f = t + i * 256;
        int node = f >> 5;
        int kc = (f & 31) * 4;
        float4 v = {0.f, 0.f, 0.f, 0.f};
        if (nb + node < V_N)
            v = *(const float4*)(nf + (size_t)(nb + node) * NODE_IN + kc);
        uint2 u2 = make_uint2(pk2(v.x, v.y), pk2(v.z, v.w));
        *(uint2*)&sA[node * 136 + kc] = u2;
    }
    __syncthreads();

    f32x4 acc[2][4];
    #pragma unroll
    for (int m = 0; m < 2; m++)
        #pragma unroll
        for (int tt = 0; tt < 4; tt++) acc[m][tt] = (f32x4){0.f, 0.f, 0.f, 0.f};

    #pragma unroll
    for (int ks = 0; ks < 4; ks++) {
        bf16x8 a0 = *(const bf16x8*)&sA[n15 * 136 + ks * 32 + q * 8];
        bf16x8 a1 = *(const bf16x8*)&sA[(16 + n15) * 136 + ks * 32 + q * 8];
        #pragma unroll
        for (int tt = 0; tt < 4; tt++) {
            int nt = (tt < 2) ? (2 * w + tt) : (8 + 2 * w + (tt - 2));
            bf16x8 b = *(const bf16x8*)(bfrag + ((size_t)(nt * 4 + ks) * 64 + lane) * 8);
            acc[0][tt] = __builtin_amdgcn_mfma_f32_16x16x32_bf16(a0, b, acc[0][tt], 0, 0, 0);
            acc[1][tt] = __builtin_amdgcn_mfma_f32_16x16x32_bf16(a1, b, acc[1][tt], 0, 0, 0);
        }
    }

    // el/er for head w (all waves busy)
    {
        float al0 = attn_l[w * 32 + n15];
        float al1 = attn_l[w * 32 + 16 + n15];
        float ar0 = attn_r[w * 32 + n15];
        float ar1 = attn_r[w * 32 + 16 + n15];
        #pragma unroll
        for (int m = 0; m < 2; m++) {
            #pragma unroll
            for (int r = 0; r < 4; r++) {
                float fa = acc[m][0][r], fb = acc[m][1][r];
                float elp = fa * al0 + fb * al1;
                float erp = fa * ar0 + fb * ar1;
                elp += __shfl_xor(elp, 1); erp += __shfl_xor(erp, 1);
                elp += __shfl_xor(elp, 2); erp += __shfl_xor(erp, 2);
                elp += __shfl_xor(elp, 4); erp += __shfl_xor(erp, 4);
                elp += __shfl_xor(elp, 8); erp += __shfl_xor(erp, 8);
                int node = nb + m * 16 + q * 4 + r;
                if (n15 == 0 && node < V_N) {
                    el[node * 4 + w] = elp;
                    er[node * 4 + w] = erp;
                }
            }
        }
    }
    // ft f16 store, head-major: uint idx = node*64 + w*16 + n15
    #pragma unroll
    for (int m = 0; m < 2; m++)
        #pragma unroll
        for (int r = 0; r < 4; r++) {
            int node = nb + m * 16 + q * 4 + r;
            if (node < V_N)
                ftw[(size_t)node * 64 + w * 16 + n15] =
                    pkh2(acc[m][0][r], acc[m][1][r]);
        }
    __syncthreads();

    // residual: wave w stages cols 32w..32w+31 (tt=2,3)
    #pragma unroll
    for (int m = 0; m < 2; m++)
        #pragma unroll
        for (int tt = 2; tt < 4; tt++)
            #pragma unroll
            for (int r = 0; r < 4; r++)
                sSf[(m * 16 + q * 4 + r) * 140 + w * 32 + (tt - 2) * 16 + n15] =
                    acc[m][tt][r];
    __syncthreads();
    #pragma unroll
    for (int i = 0; i < 4; i++) {
        int u = t + i * 256;
        int node = u >> 5, c4 = (u & 31) * 4;
        if (nb + node < V_N) {
            float4 v = *(float4*)&sSf[node * 140 + c4];
            float4 b4 = *(const float4*)(bias + c4);
            v.x += b4.x; v.y += b4.y; v.z += b4.z; v.w += b4.w;
            *(float4*)(out + (size_t)(nb + node) * HF + c4) = v;
        }
    }
}

// K3: bin. 512 edges/block. Stage all ee in LDS with ONE barrier, then 2
// independent edges/thread: LDS-cursor scatter to bucket-grouped recb.
// Cursor row H[b*NBUCKET + i] is contiguous (coalesced load).
__global__ __launch_bounds__(256) void k_bin(
    const float* __restrict__ ef, const int* __restrict__ src,
    const int* __restrict__ dst, const float* __restrict__ watt,
    const float* __restrict__ el, const int* __restrict__ H,
    uint4* __restrict__ recb)
{
    __shared__ float sw[64];
    __shared__ __align__(16) float see[PSZ][4];
    __shared__ int boff[NBUCKET];
    const int t = threadIdx.x;
    const int b = blockIdx.x;
    if (t < 64) sw[t] = watt[t];
    for (int i = t; i < NBUCKET; i += 256) boff[i] = H[b * NBUCKET + i];
    __syncthreads();
    const int lane = t & 63, w = t >> 6;
    const int k0 = (lane & 3) * 4;

    // phase 1: quad (4 lanes) per edge; lane reads 16B of the 64B ef row
    #pragma unroll
    for (int r = 0; r < 8; r++) {
        int le = w * 128 + r * 16 + (lane >> 2);    // local edge 0..511
        int ge = b * PSZ + le;
        float4 v = {0.f, 0.f, 0.f, 0.f};
        if (ge < E_N)
            v = *(const float4*)(ef + (size_t)ge * EDGE_IN + k0);
        float e0 = 0.f, e1 = 0.f, e2 = 0.f, e3 = 0.f;
        float vv[4] = {v.x, v.y, v.z, v.w};
        #pragma unroll
        for (int j = 0; j < 4; j++) {
            int k = k0 + j;
            e0 += vv[j] * sw[k * 4 + 0];
            e1 += vv[j] * sw[k * 4 + 1];
            e2 += vv[j] * sw[k * 4 + 2];
            e3 += vv[j] * sw[k * 4 + 3];
        }
        e0 += __shfl_xor(e0, 1); e1 += __shfl_xor(e1, 1);
        e2 += __shfl_xor(e2, 1); e3 += __shfl_xor(e3, 1);
        e0 += __shfl_xor(e0, 2); e1 += __shfl_xor(e1, 2);
        e2 += __shfl_xor(e2, 2); e3 += __shfl_xor(e3, 2);
        if ((lane & 3) == 0) {
            float4 o = {e0, e1, e2, e3};
            *(float4*)&see[le][0] = o;
        }
    }
    __syncthreads();

    // phase 2: 2 independent edges/thread
    #pragma unroll
    for (int c = 0; c < 2; c++) {
        int le = c * 256 + t;
        int e = b * PSZ + le;
        if (e < E_N) {
            int s = src[e], d = dst[e];
            int p = atomicAdd(&boff[d >> 6], 1);
            float4 ee = *(float4*)&see[le][0];
            float4 el4 = *(const float4*)(el + (size_t)s * 4);
            uint4 rr;
            rr.x = (unsigned)s;
            rr.y = pk2(el4.x + ee.x, el4.y + ee.y);
            rr.z = pk2(el4.z + ee.z, el4.w + ee.w);
            rr.w = (unsigned)d;
            recb[p] = rr;
        }
    }
}

// K4: fused group+gather. One block per bucket (64 dsts, ~1024 records):
// pass A: load records, compute ex (packed dup-half2 per head), per-dst LDS
// hist. Scan 64 counters (wave 0). Build u16 permutation indices. Gather
// straight from LDS: 16-lane group x 4 dsts; si broadcast via LDS; per-lane
// scalar s accumulation (no cross-lane reduction); out RMW epilogue.
__global__ __launch_bounds__(256) void k_fuse(
    const int* __restrict__ binsum, const uint4* __restrict__ recb,
    const float* __restrict__ er, const unsigned* __restrict__ ftw,
    float* __restrict__ out)
{
    __shared__ int ssi[LCAP];
    __shared__ unsigned char sdl[LCAP];
    __shared__ unsigned saw[LCAP][4];
    __shared__ unsigned short sidx[LCAP];
    __shared__ int scnt[64], sbase[64], scur[64];

    const int t = threadIdx.x;
    const int b = blockIdx.x;
    const int size = min(binsum[b], LCAP);
    const int src0 = b * CAP;

    if (t < 64) scnt[t] = 0;
    __syncthreads();

    // pass A
    for (int i = t; i < size; i += 256) {
        uint4 r = recb[src0 + i];
        int d = (int)r.w;
        const float4 er4 = *(const float4*)(er + (size_t)d * 4);
        float x0 = bflo(r.y) + er4.x;
        float x1 = bfhi(r.y) + er4.y;
        float x2 = bflo(r.z) + er4.z;
        float x3 = bfhi(r.z) + er4.w;
        x0 = x0 >= 0.f ? x0 : NEG_SLOPE * x0;
        x1 = x1 >= 0.f ? x1 : NEG_SLOPE * x1;
        x2 = x2 >= 0.f ? x2 : NEG_SLOPE * x2;
        x3 = x3 >= 0.f ? x3 : NEG_SLOPE * x3;
        float e0 = __expf(x0), e1 = __expf(x1);
        float e2 = __expf(x2), e3 = __expf(x3);
        saw[i][0] = pkh2(e0, e0); saw[i][1] = pkh2(e1, e1);
        saw[i][2] = pkh2(e2, e2); saw[i][3] = pkh2(e3, e3);
        ssi[i] = (int)r.x;
        int dl = d & 63;
        sdl[i] = (unsigned char)dl;
        atomicAdd(&scnt[dl], 1);
    }
    __syncthreads();

    // scan 64 counters (wave 0)
    if (t < 64) {
        int v = scnt[t];
        int x = v;
        #pragma unroll
        for (int off = 1; off < 64; off <<= 1) {
            int u = __shfl_up(x, off);
            if (t >= off) x += u;
        }
        sbase[t] = x - v;
        scur[t] = x - v;
    }
    __syncthreads();

    // permutation indices
    for (int i = t; i < size; i += 256) {
        int p = atomicAdd(&scur[sdl[i]], 1);
        sidx[p] = (unsigned short)i;
    }
    __syncthreads();

    // gather
    const int g = t >> 4;
    const int li = t & 15;
    const int head = li >> 2;
    #pragma unroll
    for (int dq = 0; dq < 4; dq++) {
        int dl = g + dq * 16;
        int deg = scnt[dl];
        if (deg == 0) continue;
        int n0 = sbase[dl];
        int dglob = (b << 6) + dl;
        __half2 ha0 = u2h(0u), ha1 = u2h(0u), ha2 = u2h(0u), ha3 = u2h(0u);
        __half2 hb0 = u2h(0u), hb1 = u2h(0u), hb2 = u2h(0u), hb3 = u2h(0u);
        float s = 0.f;
        int e = 0;
        for (; e + 1 < deg; e += 2) {
            int i0 = sidx[n0 + e], i1 = sidx[n0 + e + 1];
            int s0 = ssi[i0], s1 = ssi[i1];
            unsigned a0 = saw[i0][head], a1 = saw[i1][head];
            uint4 w0 = *(const uint4*)(ftw + (size_t)s0 * 64 + li * 4);
            uint4 w1 = *(const uint4*)(ftw + (size_t)s1 * 64 + li * 4);
            ha0 = __hfma2(u2h(w0.x), u2h(a0), ha0);
            ha1 = __hfma2(u2h(w0.y), u2h(a0), ha1);
            ha2 = __hfma2(u2h(w0.z), u2h(a0), ha2);
            ha3 = __hfma2(u2h(w0.w), u2h(a0), ha3);
            hb0 = __hfma2(u2h(w1.x), u2h(a1), hb0);
            hb1 = __hfma2(u2h(w1.y), u2h(a1), hb1);
            hb2 = __hfma2(u2h(w1.z), u2h(a1), hb2);
            hb3 = __hfma2(u2h(w1.w), u2h(a1), hb3);
            s += __low2float(u2h(a0)) + __low2float(u2h(a1));
        }
        if (e < deg) {
            int i0 = sidx[n0 + e];
            int s0 = ssi[i0];
            unsigned a0 = saw[i0][head];
            uint4 w0 = *(const uint4*)(ftw + (size_t)s0 * 64 + li * 4);
            ha0 = __hfma2(u2h(w0.x), u2h(a0), ha0);
            ha1 = __hfma2(u2h(w0.y), u2h(a0), ha1);
            ha2 = __hfma2(u2h(w0.z), u2h(a0), ha2);
            ha3 = __hfma2(u2h(w0.w), u2h(a0), ha3);
            s += __low2float(u2h(a0));
        }
        ha0 = __hadd2(ha0, hb0); ha1 = __hadd2(ha1, hb1);
        ha2 = __hadd2(ha2, hb2); ha3 = __hadd2(ha3, hb3);

        float rsv = 1.f / s;
        float* op = out + (size_t)dglob * HF + head * 32 + (li & 3) * 4;
        float4 r0 = *(float4*)op;
        r0.x += __low2float(ha0) * rsv; r0.y += __low2float(ha1) * rsv;
        r0.z += __low2float(ha2) * rsv; r0.w += __low2float(ha3) * rsv;
        *(float4*)op = r0;
        float4 r1 = *(float4*)(op + 16);
        r1.x += __high2float(ha0) * rsv; r1.y += __high2float(ha1) * rsv;
        r1.z += __high2float(ha2) * rsv; r1.w += __high2float(ha3) * rsv;
        *(float4*)(op + 16) = r1;
    }
}

extern "C" void kernel_launch(void* const* d_in, const int* in_sizes, int n_in,
                              void* d_out, int out_size, void* d_ws, size_t ws_size,
                              hipStream_t stream) {
    const float* nf     = (const float*)d_in[0];
    const float* ef     = (const float*)d_in[1];
    const int*   src    = (const int*)d_in[2];
    const int*   dst    = (const int*)d_in[3];
    const float* Wn     = (const float*)d_in[4];
    const float* We     = (const float*)d_in[5];
    const float* attn_l = (const float*)d_in[6];
    const float* attn_r = (const float*)d_in[7];
    const float* attn_e = (const float*)d_in[8];
    const float* Wr     = (const float*)d_in[9];
    const float* bias   = (const float*)d_in[10];
    float* out = (float*)d_out;

    unsigned* wsw  = (unsigned*)d_ws;
    unsigned* ftw  = wsw + OFF_FT;
    float* el      = (float*)(wsw + OFF_EL);
    float* er      = (float*)(wsw + OFF_ER);
    int* H         = (int*)(wsw + OFF_H);
    int* binsum    = (int*)(wsw + OFF_BSUM);
    float* watt    = (float*)(wsw + OFF_WATT);
    unsigned* bfrag = wsw + OFF_BFRAG;
    uint4* recb    = (uint4*)(wsw + OFF_RECB);

    k_prephist<<<PREP_BLKS + NPART, 256, 0, stream>>>(
        We, attn_e, Wn, Wr, dst, watt, bfrag, H);
    k_nodescan<<<NSCAN + NODE_BLKS, 256, 0, stream>>>(
        nf, bfrag, attn_l, attn_r, bias, ftw, el, er, out, H, binsum);
    k_bin<<<NPART, 256, 0, stream>>>(ef, src, dst, watt, el, H, binsum ? recb : recb);
    k_fuse<<<NBUCKET, 256, 0, stream>>>(binsum, recb, er, ftw, out);
}

// Round 14
// 206.308 us; speedup vs baseline: 1.1051x; 1.1051x over previous
//
#include <hip/hip_runtime.h>
#include <hip/hip_fp16.h>
#include <cstdint>

#define V_N 50000
#define E_N 800000
#define NODE_IN 128
#define EDGE_IN 16
#define HF 128
#define NEG_SLOPE 0.2f
#define NBUCKET 782     // ceil(50000/64) coarse dst buckets (dst>>6)
#define NPART 1563      // edge partitions of 512 (last partial: 256)
#define PSZ 512
#define CAP 2048        // fixed recb capacity per bucket (expected 1024)
#define LCAP 1536       // LDS record capacity in k_fuse (expected 1024, +16sigma)
#define NSCAN 49        // ceil(NBUCKET/16) scan blocks, 16 bins each
#define PPG 98          // parts per group: ceil(NPART/16); 7 chunks of 14
#define NODE_BLKS 1563  // ceil(50000/32)
#define PREP_BLKS 64

// ---- workspace layout (4-byte word offsets) ----
#define OFF_FT    0         // V*64 words (f16 ft, head-major)
#define OFF_EL    3200000   // V*4
#define OFF_ER    3400000   // V*4
#define OFF_H     3600000   // NPART*NBUCKET ints = 1222266 (H[part][bin])
#define OFF_BSUM  4822272   // NBUCKET ints (+pad)
#define OFF_WATT  4823056   // 64
#define OFF_BFRAG 4823120   // 16384 words (16B-aligned)
#define OFF_RECB  4839504   // NBUCKET*CAP*4 words = 6406144 (16B-aligned)
// total ~11.25M words = 45.0 MB

typedef short bf16x8 __attribute__((ext_vector_type(8)));
typedef float f32x4 __attribute__((ext_vector_type(4)));

__device__ __forceinline__ unsigned short f2bf(float f) {
    unsigned u = __float_as_uint(f);
    u += 0x7fffu + ((u >> 16) & 1u);   // round-to-nearest-even
    return (unsigned short)(u >> 16);
}
__device__ __forceinline__ unsigned pk2(float lo, float hi) {
    return (unsigned)f2bf(lo) | ((unsigned)f2bf(hi) << 16);
}
__device__ __forceinline__ float bflo(unsigned w) { return __uint_as_float(w << 16); }
__device__ __forceinline__ float bfhi(unsigned w) { return __uint_as_float(w & 0xffff0000u); }

typedef __fp16 fp16x2 __attribute__((ext_vector_type(2)));
__device__ __forceinline__ unsigned pkh2(float a, float b) {
    fp16x2 h = __builtin_amdgcn_cvt_pkrtz(a, b);   // v_cvt_pkrtz_f16_f32
    return __builtin_bit_cast(unsigned, h);
}
__device__ __forceinline__ __half2 u2h(unsigned u) {
    return __builtin_bit_cast(__half2, u);
}
__device__ __forceinline__ unsigned h2u(__half2 h) {
    return __builtin_bit_cast(unsigned, h);
}

// K1: prep (blocks < PREP_BLKS: watt + bfrag) ∥ bucket-hist (LDS, no global
// atomics): partition hb covers edges [hb*512, hb*512+512).
// H row-major by partition: H[hb*NBUCKET + bin] -> contiguous row write.
__global__ __launch_bounds__(256) void k_prephist(
    const float* __restrict__ We, const float* __restrict__ attn_e,
    const float* __restrict__ Wn, const float* __restrict__ Wr,
    const int* __restrict__ dst,
    float* __restrict__ watt, unsigned* __restrict__ bfrag,
    int* __restrict__ H)
{
    const int t = threadIdx.x;
    if (blockIdx.x >= PREP_BLKS) {
        int hb = blockIdx.x - PREP_BLKS;
        __shared__ int h[NBUCKET];
        for (int i = t; i < NBUCKET; i += 256) h[i] = 0;
        __syncthreads();
        #pragma unroll
        for (int c = 0; c < 2; c++) {
            int e = hb * PSZ + c * 256 + t;
            if (e < E_N) atomicAdd(&h[dst[e] >> 6], 1);
        }
        __syncthreads();
        for (int i = t; i < NBUCKET; i += 256) H[hb * NBUCKET + i] = h[i];
        return;
    }
    int g = blockIdx.x * 256 + t;
    if (blockIdx.x == 0 && t < 64) {
        int k = t >> 2, hh = t & 3;
        float s = 0.f;
        #pragma unroll
        for (int f = 0; f < 32; f++)
            s += We[k * HF + hh * 32 + f] * attn_e[hh * 32 + f];
        watt[k * 4 + hh] = s;
    }
    // g < 16384 always (64 blocks x 256)
    {
        int c    = g >> 8;
        int lane = (g >> 2) & 63;
        int jp   = g & 3;
        int nt = c >> 2, ks = c & 3;
        int col = nt * 16 + (lane & 15);
        int k   = ks * 32 + (lane >> 4) * 8 + jp * 2;
        const float* W = (col < 128) ? Wn : Wr;
        int cc = col & 127;
        float x0 = W[(size_t)k * 128 + cc];
        float x1 = W[(size_t)(k + 1) * 128 + cc];
        bfrag[g] = pk2(x0, x1);
    }
}

// K2: blocks [0,NSCAN) = tiled cursor scan (16 bins/block, 16 part-groups;
// the 16 lanes of a group read 16 CONSECUTIVE bins = one 64B line per
// (part, bin-chunk) -> H coalesced; per-thread work pipelined via 7 chunks
// of 14 register-preloaded values; per-bin cross-group prefix via 16-step
// LDS scan; absolute cursors via bin*CAP base) ∥ node MFMA.
__global__ __launch_bounds__(256) void k_nodescan(
    const float* __restrict__ nf, const unsigned* __restrict__ bfragw,
    const float* __restrict__ attn_l, const float* __restrict__ attn_r,
    const float* __restrict__ bias,
    unsigned* __restrict__ ftw, float* __restrict__ el,
    float* __restrict__ er, float* __restrict__ out,
    int* __restrict__ H, int* __restrict__ binsum)
{
    __shared__ __align__(16) float sSf[32 * 140];
    unsigned short* sA = (unsigned short*)sSf;      // stride 136 bf16/row

    if (blockIdx.x < NSCAN) {
        int* ssum = (int*)sSf;
        const int t = threadIdx.x;
        const int bi = t & 15, bg = t >> 4;
        const int bin = blockIdx.x * 16 + bi;
        const int p0 = bg * PPG;
        const bool ok = bin < NBUCKET;
        int ls = 0;
        if (ok) {
            #pragma unroll
            for (int c = 0; c < 7; c++) {
                int v[14];
                #pragma unroll
                for (int j = 0; j < 14; j++) {
                    int p = p0 + c * 14 + j;
                    v[j] = (p < NPART) ? H[(size_t)p * NBUCKET + bin] : 0;
                }
                #pragma unroll
                for (int j = 0; j < 14; j++) ls += v[j];
            }
        }
        ssum[t] = ls;
        __syncthreads();
        // per-bin inclusive scan over the 16 groups (stride-16 in LDS)
        #pragma unroll
        for (int off = 1; off < 16; off <<= 1) {
            int u = (bg >= off) ? ssum[t - off * 16] : 0;
            __syncthreads();
            ssum[t] += u;
            __syncthreads();
        }
        if (ok) {
            int cacc = bin * CAP + ssum[t] - ls;   // exclusive prefix
            #pragma unroll
            for (int c = 0; c < 7; c++) {
                int v[14];
                #pragma unroll
                for (int j = 0; j < 14; j++) {
                    int p = p0 + c * 14 + j;
                    v[j] = (p < NPART) ? H[(size_t)p * NBUCKET + bin] : 0;
                }
                #pragma unroll
                for (int j = 0; j < 14; j++) {
                    int p = p0 + c * 14 + j;
                    if (p < NPART) H[(size_t)p * NBUCKET + bin] = cacc;
                    cacc += v[j];
                }
            }
            if (bg == 15) binsum[bin] = ssum[t];
        }
        return;
    }

    const int t = threadIdx.x;
    const int lane = t & 63;
    const int w = t >> 6;                            // == head
    const int nb = (blockIdx.x - NSCAN) * 32;
    const int n15 = lane & 15;
    const int q = lane >> 4;
    const unsigned short* bfrag = (const unsigned short*)bfragw;

    #pragma unroll
    for (int i = 0; i < 4; i++) {
        int f = t + i * 256;
        int node = f >> 5;
        int kc = (f & 31) * 4;
        float4 v = {0.f, 0.f, 0.f, 0.f};
        if (nb + node < V_N)
            v = *(const float4*)(nf + (size_t)(nb + node) * NODE_IN + kc);
        uint2 u2 = make_uint2(pk2(v.x, v.y), pk2(v.z, v.w));
        *(uint2*)&sA[node * 136 + kc] = u2;
    }
    __syncthreads();

    f32x4 acc[2][4];
    #pragma unroll
    for (int m = 0; m < 2; m++)
        #pragma unroll
        for (int tt = 0; tt < 4; tt++) acc[m][tt] = (f32x4){0.f, 0.f, 0.f, 0.f};

    #pragma unroll
    for (int ks = 0; ks < 4; ks++) {
        bf16x8 a0 = *(const bf16x8*)&sA[n15 * 136 + ks * 32 + q * 8];
        bf16x8 a1 = *(const bf16x8*)&sA[(16 + n15) * 136 + ks * 32 + q * 8];
        #pragma unroll
        for (int tt = 0; tt < 4; tt++) {
            int nt = (tt < 2) ? (2 * w + tt) : (8 + 2 * w + (tt - 2));
            bf16x8 b = *(const bf16x8*)(bfrag + ((size_t)(nt * 4 + ks) * 64 + lane) * 8);
            acc[0][tt] = __builtin_amdgcn_mfma_f32_16x16x32_bf16(a0, b, acc[0][tt], 0, 0, 0);
            acc[1][tt] = __builtin_amdgcn_mfma_f32_16x16x32_bf16(a1, b, acc[1][tt], 0, 0, 0);
        }
    }

    // el/er for head w (all waves busy)
    {
        float al0 = attn_l[w * 32 + n15];
        float al1 = attn_l[w * 32 + 16 + n15];
        float ar0 = attn_r[w * 32 + n15];
        float ar1 = attn_r[w * 32 + 16 + n15];
        #pragma unroll
        for (int m = 0; m < 2; m++) {
            #pragma unroll
            for (int r = 0; r < 4; r++) {
                float fa = acc[m][0][r], fb = acc[m][1][r];
                float elp = fa * al0 + fb * al1;
                float erp = fa * ar0 + fb * ar1;
                elp += __shfl_xor(elp, 1); erp += __shfl_xor(erp, 1);
                elp += __shfl_xor(elp, 2); erp += __shfl_xor(erp, 2);
                elp += __shfl_xor(elp, 4); erp += __shfl_xor(erp, 4);
                elp += __shfl_xor(elp, 8); erp += __shfl_xor(erp, 8);
                int node = nb + m * 16 + q * 4 + r;
                if (n15 == 0 && node < V_N) {
                    el[node * 4 + w] = elp;
                    er[node * 4 + w] = erp;
                }
            }
        }
    }
    // ft f16 store, head-major: uint idx = node*64 + w*16 + n15
    #pragma unroll
    for (int m = 0; m < 2; m++)
        #pragma unroll
        for (int r = 0; r < 4; r++) {
            int node = nb + m * 16 + q * 4 + r;
            if (node < V_N)
                ftw[(size_t)node * 64 + w * 16 + n15] =
                    pkh2(acc[m][0][r], acc[m][1][r]);
        }
    __syncthreads();

    // residual: wave w stages cols 32w..32w+31 (tt=2,3)
    #pragma unroll
    for (int m = 0; m < 2; m++)
        #pragma unroll
        for (int tt = 2; tt < 4; tt++)
            #pragma unroll
            for (int r = 0; r < 4; r++)
                sSf[(m * 16 + q * 4 + r) * 140 + w * 32 + (tt - 2) * 16 + n15] =
                    acc[m][tt][r];
    __syncthreads();
    #pragma unroll
    for (int i = 0; i < 4; i++) {
        int u = t + i * 256;
        int node = u >> 5, c4 = (u & 31) * 4;
        if (nb + node < V_N) {
            float4 v = *(float4*)&sSf[node * 140 + c4];
            float4 b4 = *(const float4*)(bias + c4);
            v.x += b4.x; v.y += b4.y; v.z += b4.z; v.w += b4.w;
            *(float4*)(out + (size_t)(nb + node) * HF + c4) = v;
        }
    }
}

// K3: bin. 512 edges/block. Stage all ee in LDS with ONE barrier, then 2
// independent edges/thread: LDS-cursor scatter to bucket-grouped recb.
// Cursor row H[b*NBUCKET + i] is contiguous (coalesced load).
__global__ __launch_bounds__(256) void k_bin(
    const float* __restrict__ ef, const int* __restrict__ src,
    const int* __restrict__ dst, const float* __restrict__ watt,
    const float* __restrict__ el, const int* __restrict__ H,
    uint4* __restrict__ recb)
{
    __shared__ float sw[64];
    __shared__ __align__(16) float see[PSZ][4];
    __shared__ int boff[NBUCKET];
    const int t = threadIdx.x;
    const int b = blockIdx.x;
    if (t < 64) sw[t] = watt[t];
    for (int i = t; i < NBUCKET; i += 256) boff[i] = H[b * NBUCKET + i];
    __syncthreads();
    const int lane = t & 63, w = t >> 6;
    const int k0 = (lane & 3) * 4;

    // phase 1: quad (4 lanes) per edge; lane reads 16B of the 64B ef row
    #pragma unroll
    for (int r = 0; r < 8; r++) {
        int le = w * 128 + r * 16 + (lane >> 2);    // local edge 0..511
        int ge = b * PSZ + le;
        float4 v = {0.f, 0.f, 0.f, 0.f};
        if (ge < E_N)
            v = *(const float4*)(ef + (size_t)ge * EDGE_IN + k0);
        float e0 = 0.f, e1 = 0.f, e2 = 0.f, e3 = 0.f;
        float vv[4] = {v.x, v.y, v.z, v.w};
        #pragma unroll
        for (int j = 0; j < 4; j++) {
            int k = k0 + j;
            e0 += vv[j] * sw[k * 4 + 0];
            e1 += vv[j] * sw[k * 4 + 1];
            e2 += vv[j] * sw[k * 4 + 2];
            e3 += vv[j] * sw[k * 4 + 3];
        }
        e0 += __shfl_xor(e0, 1); e1 += __shfl_xor(e1, 1);
        e2 += __shfl_xor(e2, 1); e3 += __shfl_xor(e3, 1);
        e0 += __shfl_xor(e0, 2); e1 += __shfl_xor(e1, 2);
        e2 += __shfl_xor(e2, 2); e3 += __shfl_xor(e3, 2);
        if ((lane & 3) == 0) {
            float4 o = {e0, e1, e2, e3};
            *(float4*)&see[le][0] = o;
        }
    }
    __syncthreads();

    // phase 2: 2 independent edges/thread
    #pragma unroll
    for (int c = 0; c < 2; c++) {
        int le = c * 256 + t;
        int e = b * PSZ + le;
        if (e < E_N) {
            int s = src[e], d = dst[e];
            int p = atomicAdd(&boff[d >> 6], 1);
            float4 ee = *(float4*)&see[le][0];
            float4 el4 = *(const float4*)(el + (size_t)s * 4);
            uint4 rr;
            rr.x = (unsigned)s;
            rr.y = pk2(el4.x + ee.x, el4.y + ee.y);
            rr.z = pk2(el4.z + ee.z, el4.w + ee.w);
            rr.w = (unsigned)d;
            recb[p] = rr;
        }
    }
}

// K4: fused group+gather. One block per bucket (64 dsts, ~1024 records):
// pass A: load records, compute ex (packed dup-half2 per head), per-dst LDS
// hist. Scan 64 counters (wave 0). Build u16 permutation indices. Gather
// straight from LDS: 16-lane group x 4 dsts; si broadcast via LDS; per-lane
// scalar s accumulation (no cross-lane reduction); out RMW epilogue.
__global__ __launch_bounds__(256) void k_fuse(
    const int* __restrict__ binsum, const uint4* __restrict__ recb,
    const float* __restrict__ er, const unsigned* __restrict__ ftw,
    float* __restrict__ out)
{
    __shared__ int ssi[LCAP];
    __shared__ unsigned char sdl[LCAP];
    __shared__ unsigned saw[LCAP][4];
    __shared__ unsigned short sidx[LCAP];
    __shared__ int scnt[64], sbase[64], scur[64];

    const int t = threadIdx.x;
    const int b = blockIdx.x;
    const int size = min(binsum[b], LCAP);
    const int src0 = b * CAP;

    if (t < 64) scnt[t] = 0;
    __syncthreads();

    // pass A
    for (int i = t; i < size; i += 256) {
        uint4 r = recb[src0 + i];
        int d = (int)r.w;
        const float4 er4 = *(const float4*)(er + (size_t)d * 4);
        float x0 = bflo(r.y) + er4.x;
        float x1 = bfhi(r.y) + er4.y;
        float x2 = bflo(r.z) + er4.z;
        float x3 = bfhi(r.z) + er4.w;
        x0 = x0 >= 0.f ? x0 : NEG_SLOPE * x0;
        x1 = x1 >= 0.f ? x1 : NEG_SLOPE * x1;
        x2 = x2 >= 0.f ? x2 : NEG_SLOPE * x2;
        x3 = x3 >= 0.f ? x3 : NEG_SLOPE * x3;
        float e0 = __expf(x0), e1 = __expf(x1);
        float e2 = __expf(x2), e3 = __expf(x3);
        saw[i][0] = pkh2(e0, e0); saw[i][1] = pkh2(e1, e1);
        saw[i][2] = pkh2(e2, e2); saw[i][3] = pkh2(e3, e3);
        ssi[i] = (int)r.x;
        int dl = d & 63;
        sdl[i] = (unsigned char)dl;
        atomicAdd(&scnt[dl], 1);
    }
    __syncthreads();

    // scan 64 counters (wave 0)
    if (t < 64) {
        int v = scnt[t];
        int x = v;
        #pragma unroll
        for (int off = 1; off < 64; off <<= 1) {
            int u = __shfl_up(x, off);
            if (t >= off) x += u;
        }
        sbase[t] = x - v;
        scur[t] = x - v;
    }
    __syncthreads();

    // permutation indices
    for (int i = t; i < size; i += 256) {
        int p = atomicAdd(&scur[sdl[i]], 1);
        sidx[p] = (unsigned short)i;
    }
    __syncthreads();

    // gather
    const int g = t >> 4;
    const int li = t & 15;
    const int head = li >> 2;
    #pragma unroll
    for (int dq = 0; dq < 4; dq++) {
        int dl = g + dq * 16;
        int deg = scnt[dl];
        if (deg == 0) continue;
        int n0 = sbase[dl];
        int dglob = (b << 6) + dl;
        __half2 ha0 = u2h(0u), ha1 = u2h(0u), ha2 = u2h(0u), ha3 = u2h(0u);
        __half2 hb0 = u2h(0u), hb1 = u2h(0u), hb2 = u2h(0u), hb3 = u2h(0u);
        float s = 0.f;
        int e = 0;
        for (; e + 1 < deg; e += 2) {
            int i0 = sidx[n0 + e], i1 = sidx[n0 + e + 1];
            int s0 = ssi[i0], s1 = ssi[i1];
            unsigned a0 = saw[i0][head], a1 = saw[i1][head];
            uint4 w0 = *(const uint4*)(ftw + (size_t)s0 * 64 + li * 4);
            uint4 w1 = *(const uint4*)(ftw + (size_t)s1 * 64 + li * 4);
            ha0 = __hfma2(u2h(w0.x), u2h(a0), ha0);
            ha1 = __hfma2(u2h(w0.y), u2h(a0), ha1);
            ha2 = __hfma2(u2h(w0.z), u2h(a0), ha2);
            ha3 = __hfma2(u2h(w0.w), u2h(a0), ha3);
            hb0 = __hfma2(u2h(w1.x), u2h(a1), hb0);
            hb1 = __hfma2(u2h(w1.y), u2h(a1), hb1);
            hb2 = __hfma2(u2h(w1.z), u2h(a1), hb2);
            hb3 = __hfma2(u2h(w1.w), u2h(a1), hb3);
            s += __low2float(u2h(a0)) + __low2float(u2h(a1));
        }
        if (e < deg) {
            int i0 = sidx[n0 + e];
            int s0 = ssi[i0];
            unsigned a0 = saw[i0][head];
            uint4 w0 = *(const uint4*)(ftw + (size_t)s0 * 64 + li * 4);
            ha0 = __hfma2(u2h(w0.x), u2h(a0), ha0);
            ha1 = __hfma2(u2h(w0.y), u2h(a0), ha1);
            ha2 = __hfma2(u2h(w0.z), u2h(a0), ha2);
            ha3 = __hfma2(u2h(w0.w), u2h(a0), ha3);
            s += __low2float(u2h(a0));
        }
        ha0 = __hadd2(ha0, hb0); ha1 = __hadd2(ha1, hb1);
        ha2 = __hadd2(ha2, hb2); ha3 = __hadd2(ha3, hb3);

        float rsv = 1.f / s;
        float* op = out + (size_t)dglob * HF + head * 32 + (li & 3) * 4;
        float4 r0 = *(float4*)op;
        r0.x += __low2float(ha0) * rsv; r0.y += __low2float(ha1) * rsv;
        r0.z += __low2float(ha2) * rsv; r0.w += __low2float(ha3) * rsv;
        *(float4*)op = r0;
        float4 r1 = *(float4*)(op + 16);
        r1.x += __high2float(ha0) * rsv; r1.y += __high2float(ha1) * rsv;
        r1.z += __high2float(ha2) * rsv; r1.w += __high2float(ha3) * rsv;
        *(float4*)(op + 16) = r1;
    }
}

extern "C" void kernel_launch(void* const* d_in, const int* in_sizes, int n_in,
                              void* d_out, int out_size, void* d_ws, size_t ws_size,
                              hipStream_t stream) {
    const float* nf     = (const float*)d_in[0];
    const float* ef     = (const float*)d_in[1];
    const int*   src    = (const int*)d_in[2];
    const int*   dst    = (const int*)d_in[3];
    const float* Wn     = (const float*)d_in[4];
    const float* We     = (const float*)d_in[5];
    const float* attn_l = (const float*)d_in[6];
    const float* attn_r = (const float*)d_in[7];
    const float* attn_e = (const float*)d_in[8];
    const float* Wr     = (const float*)d_in[9];
    const float* bias   = (const float*)d_in[10];
    float* out = (float*)d_out;

    unsigned* wsw  = (unsigned*)d_ws;
    unsigned* ftw  = wsw + OFF_FT;
    float* el      = (float*)(wsw + OFF_EL);
    float* er      = (float*)(wsw + OFF_ER);
    int* H         = (int*)(wsw + OFF_H);
    int* binsum    = (int*)(wsw + OFF_BSUM);
    float* watt    = (float*)(wsw + OFF_WATT);
    unsigned* bfrag = wsw + OFF_BFRAG;
    uint4* recb    = (uint4*)(wsw + OFF_RECB);

    k_prephist<<<PREP_BLKS + NPART, 256, 0, stream>>>(
        We, attn_e, Wn, Wr, dst, watt, bfrag, H);
    k_nodescan<<<NSCAN + NODE_BLKS, 256, 0, stream>>>(
        nf, bfrag, attn_l, attn_r, bias, ftw, el, er, out, H, binsum);
    k_bin<<<NPART, 256, 0, stream>>>(ef, src, dst, watt, el, H, recb);
    k_fuse<<<NBUCKET, 256, 0, stream>>>(binsum, recb, er, ftw, out);
}